// Round 5
// baseline (134.773 us; speedup 1.0000x reference)
//
#include <hip/hip_runtime.h>

// NCC forward: X,Y (16,32,64,24) fp32, PS=5, D=2, EPS=0.01
// out[b, c*120 + yo*24 + i, h, x] =
//   (sum_{dy,dx} (Xp[h+dy,x+dx]-Em[h,x]) * Yp[h+yo+dy,i+dx]) / (25*Es[h,x] * Fs[h+yo,i])
//
// Decomposition: G(r,yo) = sum_dx Xp[r,x+dx]*Yp[r+yo,i+dx];
//                cross(h,yo) = sum_{dy=0..4} G(h+dy,yo)
// Block = (b, c, half): sweeps 36 padded rows (emits 32 output rows), 21.6KB LDS.
// Thread = (x-pair, i): 12*24 = 288 threads; float2 loads/stores along x.
// All rolling state (y rows, staggered accs) in slot-indexed register buffers;
// slot = t%5 is a template literal (step<K>), so indices are compile-time.

#define NT 288

template<int K>
__device__ __forceinline__ void step(
    int t_, int i, int xx, int r0,
    const float* __restrict__ sXp, const float* __restrict__ sYp,
    const float* __restrict__ sEm, const float* __restrict__ sIE,
    const float* __restrict__ sSF, const float* __restrict__ sIF,
    float (&y)[5][5], float (&acc)[5][2][5],
    float* __restrict__ out, size_t outBase)
{
    // X row t_ : 6-wide window (covers x and x+1 patches), 3x ds_read_b64
    float2 xA = *(const float2*)&sXp[t_*28 + xx];
    float2 xB = *(const float2*)&sXp[t_*28 + xx + 2];
    float2 xC = *(const float2*)&sXp[t_*28 + xx + 4];
    float xr[6] = {xA.x, xA.y, xB.x, xB.y, xC.x, xC.y};

    // new Y row t_+4 -> slot (K+4)%5  (slot m holds local row congruent to m mod 5)
    {
        const float* ys = &sYp[(t_+4)*28 + i];
        #pragma unroll
        for (int d = 0; d < 5; ++d) y[(K+4)%5][d] = ys[d];
    }

    // G(t_, yo) for both x positions
    float g[2][5];
    #pragma unroll
    for (int xi = 0; xi < 2; ++xi)
        #pragma unroll
        for (int yo = 0; yo < 5; ++yo) g[xi][yo] = 0.f;
    #pragma unroll
    for (int d = 0; d < 5; ++d) {
        #pragma unroll
        for (int yo = 0; yo < 5; ++yo) {
            float yv = y[(K+yo)%5][d];        // row t_+yo
            g[0][yo] = fmaf(xr[d],     yv, g[0][yo]);
            g[1][yo] = fmaf(xr[d + 1], yv, g[1][yo]);
        }
    }

    // staggered accumulation: every live window gets this row's G
    #pragma unroll
    for (int s = 0; s < 5; ++s)
        #pragma unroll
        for (int xi = 0; xi < 2; ++xi)
            #pragma unroll
            for (int yo = 0; yo < 5; ++yo)
                acc[s][xi][yo] += g[xi][yo];

    // window started at t_-4 completes now (slot (K+1)%5) -> emit h = r0+t_-4
    if (t_ >= 4) {
        const int hl = t_ - 4;
        const int h  = r0 + hl;
        float2 em2 = *(const float2*)&sEm[hl*24 + xx];
        float2 ie2 = *(const float2*)&sIE[hl*24 + xx];
        float* op = out + outBase + (size_t)h * 24;
        #pragma unroll
        for (int yo = 0; yo < 5; ++yo) {
            float sfv = sSF[(hl + yo)*24 + i];
            float ifv = sIF[(hl + yo)*24 + i];
            float2 v;
            v.x = fmaf(-em2.x, sfv, acc[(K+1)%5][0][yo]) * (ie2.x * ifv);
            v.y = fmaf(-em2.y, sfv, acc[(K+1)%5][1][yo]) * (ie2.y * ifv);
            *(float2*)(op + (size_t)yo * 36864) = v;   // yo stride = 24*1536
        }
    }
    // reset completed slot; it restarts accumulating at t_+1
    #pragma unroll
    for (int xi = 0; xi < 2; ++xi)
        #pragma unroll
        for (int yo = 0; yo < 5; ++yo)
            acc[(K+1)%5][xi][yo] = 0.f;
}

__global__ __launch_bounds__(NT, 4)
void ncc_kernel(const float* __restrict__ X, const float* __restrict__ Y,
                float* __restrict__ out)
{
    // local row j <-> absolute padded row r0+j
    __shared__ __align__(16) float sXp[36*28];  // Xp rows r0..r0+35
    __shared__ __align__(16) float sYp[40*28];  // Yp rows r0..r0+39
    __shared__ __align__(16) float sEm[32*24];  // X patch mean, h = r0..r0+31
    __shared__ __align__(16) float sIE[32*24];  // 1/(25*Es)
    __shared__ __align__(16) float sSF[36*24];  // Y patch sum, rows r0..r0+35
    __shared__ __align__(16) float sIF[36*24];  // 1/Fs

    const int tid  = threadIdx.x;
    const int bid  = blockIdx.x;
    const int half = bid & 1;
    const int c    = (bid >> 1) & 31;
    const int b    = bid >> 6;
    const int r0   = half * 32;

    const float* Xc = X + (size_t)(b*32 + c) * (64*24);
    const float* Yc = Y + (size_t)(b*32 + c) * (64*24);

    // ---- Phase A: stage padded sub-rows ----
    for (int idx = tid; idx < 36*28; idx += NT) {
        int j = idx / 28, cc = idx - j*28;
        int hh = r0 + j - 2, ww = cc - 2;            // Xp pad = 2 (H and W)
        float v = 0.f;
        if ((unsigned)hh < 64u && (unsigned)ww < 24u) v = Xc[hh*24 + ww];
        sXp[idx] = v;
    }
    for (int idx = tid; idx < 40*28; idx += NT) {
        int j = idx / 28, cc = idx - j*28;
        int hh = r0 + j - 4, ww = cc - 2;            // Yp pad = 4 (H), 2 (W)
        float v = 0.f;
        if ((unsigned)hh < 64u && (unsigned)ww < 24u) v = Yc[hh*24 + ww];
        sYp[idx] = v;
    }
    __syncthreads();

    // ---- Phase B: patch statistics ----
    for (int idx = tid; idx < 32*24; idx += NT) {
        int hl = idx / 24, xxp = idx - hl*24;
        float s = 0.f, s2 = 0.f;
        #pragma unroll
        for (int dy = 0; dy < 5; ++dy)
            #pragma unroll
            for (int dx = 0; dx < 5; ++dx) {
                float v = sXp[(hl + dy)*28 + xxp + dx];
                s += v; s2 = fmaf(v, v, s2);
            }
        float var = fmaxf((s2 - s*s*0.04f) * (1.f/24.f), 0.f);
        sEm[idx] = s * 0.04f;
        sIE[idx] = 1.f / (25.f * (sqrtf(var) + 0.01f));
    }
    for (int idx = tid; idx < 36*24; idx += NT) {
        int jl = idx / 24, ii = idx - jl*24;
        float s = 0.f, s2 = 0.f;
        #pragma unroll
        for (int dy = 0; dy < 5; ++dy)
            #pragma unroll
            for (int dx = 0; dx < 5; ++dx) {
                float v = sYp[(jl + dy)*28 + ii + dx];
                s += v; s2 = fmaf(v, v, s2);
            }
        float var = fmaxf((s2 - s*s*0.04f) * (1.f/24.f), 0.f);
        sSF[idx] = s;
        sIF[idx] = 1.f / (sqrtf(var) + 0.01f);
    }
    __syncthreads();

    // ---- Phase C: sliding-row sweep (36 steps, emit 32 rows) ----
    const int x2 = tid % 12;
    const int i  = tid / 12;                 // 0..23
    const int xx = x2 * 2;
    const size_t outBase = ((size_t)(b*3840 + c*120 + i)) * 1536 + xx;

    float y[5][5];
    #pragma unroll
    for (int m = 0; m < 4; ++m)              // slots 0..3 <- local rows 0..3
        #pragma unroll
        for (int d = 0; d < 5; ++d)
            y[m][d] = sYp[m*28 + i + d];

    float acc[5][2][5];
    #pragma unroll
    for (int s = 0; s < 5; ++s)
        #pragma unroll
        for (int xi = 0; xi < 2; ++xi)
            #pragma unroll
            for (int yo = 0; yo < 5; ++yo) acc[s][xi][yo] = 0.f;

    #pragma unroll 1
    for (int t5 = 0; t5 < 35; t5 += 5) {     // t5 multiple of 5 -> (t5+K)%5 == K
        step<0>(t5+0, i, xx, r0, sXp, sYp, sEm, sIE, sSF, sIF, y, acc, out, outBase);
        step<1>(t5+1, i, xx, r0, sXp, sYp, sEm, sIE, sSF, sIF, y, acc, out, outBase);
        step<2>(t5+2, i, xx, r0, sXp, sYp, sEm, sIE, sSF, sIF, y, acc, out, outBase);
        step<3>(t5+3, i, xx, r0, sXp, sYp, sEm, sIE, sSF, sIF, y, acc, out, outBase);
        step<4>(t5+4, i, xx, r0, sXp, sYp, sEm, sIE, sSF, sIF, y, acc, out, outBase);
    }
    step<0>(35, i, xx, r0, sXp, sYp, sEm, sIE, sSF, sIF, y, acc, out, outBase);
}

extern "C" void kernel_launch(void* const* d_in, const int* in_sizes, int n_in,
                              void* d_out, int out_size, void* d_ws, size_t ws_size,
                              hipStream_t stream) {
    const float* X = (const float*)d_in[0];
    const float* Y = (const float*)d_in[1];
    float* out = (float*)d_out;
    ncc_kernel<<<dim3(16*32*2), dim3(NT), 0, stream>>>(X, Y, out);
}

// Round 6
// 104.861 us; speedup vs baseline: 1.2853x; 1.2853x over previous
//
#include <hip/hip_runtime.h>

// NCC forward: X,Y (16,32,64,24) fp32, PS=5, D=2, EPS=0.01
// out[blk*184320 + (yo*24+i)*1536 + h*24 + x],  blk = b*32+c
//   = (cross - Em(h,x)*SF(h+yo,i)) * IE(h,x) * IF(h+yo,i)
// cross = sum_{dy,dx} Xp[h+dy][x+dx] * Yp[h+yo+dy][i+dx]
//
// Mapping: thread = (x, h) spatial (576 = 24x24, 9 waves), sweep i in time.
// -> every store = 64 consecutive (h,x) floats = 256B contiguous per wave.
// X window (25 regs) loaded once per h-tile; Y window yw[9][5] rolls along i
// with mod-5 compile-time slots (step_i<K>); Y staged TRANSPOSED [col][row]
// (pad 73, coprime with 32 banks) so roll reads are 9 consecutive floats;
// (SF,IF) interleaved float2 so the 5 per-yo reads merge to read2_b64.

#define NT 576

template<int K>
__device__ __forceinline__ void step_i(
    int i, int h,
    const float* __restrict__ sYT, const float* __restrict__ sFI,
    const float (&Xw)[5][5], float (&yw)[9][5],
    float Em, float IE, float* __restrict__ outC, int lo)
{
    // roll: new col i+4 -> slot (K+4)%5 ; 9 consecutive rows h..h+8
    const float* yc = &sYT[(i + 4) * 73 + h];
    #pragma unroll
    for (int dr = 0; dr < 9; ++dr) yw[dr][(K + 4) % 5] = yc[dr];

    // cross for 5 yo: 125 FMA, all register operands, 5 independent chains
    float cr[5] = {0.f, 0.f, 0.f, 0.f, 0.f};
    #pragma unroll
    for (int dy = 0; dy < 5; ++dy) {
        #pragma unroll
        for (int dx = 0; dx < 5; ++dx) {
            const float xv = Xw[dy][dx];
            #pragma unroll
            for (int yo = 0; yo < 5; ++yo)
                cr[yo] = fmaf(xv, yw[dy + yo][(K + dx) % 5], cr[yo]);
        }
    }

    // (SF, IF) rows h..h+4 at col i: 5 consecutive float2
    const float2* fi = (const float2*)&sFI[(i * 68 + h) * 2];
    #pragma unroll
    for (int yo = 0; yo < 5; ++yo) {
        float2 f = fi[yo];
        float v = fmaf(-Em, f.x, cr[yo]) * (IE * f.y);
        outC[(yo * 24 + i) * 1536 + lo] = v;   // uniform offset + lane offset
    }
}

__global__ __launch_bounds__(NT, 5)
void ncc_kernel(const float* __restrict__ X, const float* __restrict__ Y,
                float* __restrict__ out)
{
    __shared__ float sXp[68 * 28];        // Xp row-major, rows 0..67 (= X[-2..65])
    __shared__ float sYT[28 * 73];        // Yp TRANSPOSED [col 0..27][row 0..71]
    __shared__ float sMI[64 * 24 * 2];    // (Em, IE) interleaved per (h,x)
    __shared__ float sFI[24 * 68 * 2];    // (SF, IF) interleaved per (i, r)

    const int tid = threadIdx.x;
    const int blk = blockIdx.x;           // = b*32 + c
    const float* Xc = X + (size_t)blk * 1536;
    const float* Yc = Y + (size_t)blk * 1536;
    float* outC = out + (size_t)blk * 184320;

    // ---- Phase A: stage (coalesced global reads; transposed LDS write for Y) ----
    for (int idx = tid; idx < 68 * 28; idx += NT) {
        int r = idx / 28, cc = idx - r * 28;
        int hh = r - 2, ww = cc - 2;
        float v = 0.f;
        if ((unsigned)hh < 64u && (unsigned)ww < 24u) v = Xc[hh * 24 + ww];
        sXp[idx] = v;
    }
    for (int idx = tid; idx < 72 * 28; idx += NT) {
        int r = idx / 28, cc = idx - r * 28;
        int hh = r - 4, ww = cc - 2;
        float v = 0.f;
        if ((unsigned)hh < 64u && (unsigned)ww < 24u) v = Yc[hh * 24 + ww];
        sYT[cc * 73 + r] = v;             // stride 73: coprime w/ 32 banks
    }
    __syncthreads();

    // ---- Phase B: patch statistics ----
    for (int idx = tid; idx < 64 * 24; idx += NT) {      // X stats, xx fastest
        int hl = idx / 24, xx = idx - hl * 24;
        float s = 0.f, s2 = 0.f;
        #pragma unroll
        for (int dy = 0; dy < 5; ++dy)
            #pragma unroll
            for (int dx = 0; dx < 5; ++dx) {
                float v = sXp[(hl + dy) * 28 + xx + dx];
                s += v; s2 = fmaf(v, v, s2);
            }
        float var = fmaxf((s2 - s * s * 0.04f) * (1.f / 24.f), 0.f);
        float2 mi;
        mi.x = s * 0.04f;                                // Em
        mi.y = 1.f / (25.f * (sqrtf(var) + 0.01f));      // 1/(25*Es)
        *(float2*)&sMI[idx * 2] = mi;
    }
    for (int idx = tid; idx < 24 * 68; idx += NT) {      // Y stats, r fastest
        int ii = idx / 68, r = idx - ii * 68;
        float s = 0.f, s2 = 0.f;
        #pragma unroll
        for (int dx = 0; dx < 5; ++dx)
            #pragma unroll
            for (int dy = 0; dy < 5; ++dy) {
                float v = sYT[(ii + dx) * 73 + r + dy];  // consecutive per lane
                s += v; s2 = fmaf(v, v, s2);
            }
        float var = fmaxf((s2 - s * s * 0.04f) * (1.f / 24.f), 0.f);
        float2 fi;
        fi.x = s;                                        // SF (patch sum)
        fi.y = 1.f / (sqrtf(var) + 0.01f);               // 1/Fs
        *(float2*)&sFI[(ii * 68 + r) * 2] = fi;
    }
    __syncthreads();

    // ---- Phase C: 3 h-tiles x 24 i-steps; thread = (x, h) ----
    const int x  = tid % 24;
    const int hl = tid / 24;

    #pragma unroll 1
    for (int ht = 0; ht < 3; ++ht) {
        const int h = ht * 24 + hl;
        if (h >= 64) break;              // wave-uniform (waves 6..8 of tile 2)
        const int lo = h * 24 + x;

        float2 mi = *(const float2*)&sMI[lo * 2];
        const float Em = mi.x, IE = mi.y;

        float Xw[5][5];                  // fixed X window: loaded once, reused 120x
        #pragma unroll
        for (int dy = 0; dy < 5; ++dy)
            #pragma unroll
            for (int dx = 0; dx < 5; ++dx)
                Xw[dy][dx] = sXp[(h + dy) * 28 + x + dx];

        float yw[9][5];                  // Y window rows h..h+8, cols i..i+4
        #pragma unroll
        for (int c = 0; c < 4; ++c) {    // prefill cols 0..3 -> slots 0..3
            const float* yc = &sYT[c * 73 + h];
            #pragma unroll
            for (int dr = 0; dr < 9; ++dr) yw[dr][c] = yc[dr];
        }

        #pragma unroll 1
        for (int t5 = 0; t5 < 20; t5 += 5) {
            step_i<0>(t5 + 0, h, sYT, sFI, Xw, yw, Em, IE, outC, lo);
            step_i<1>(t5 + 1, h, sYT, sFI, Xw, yw, Em, IE, outC, lo);
            step_i<2>(t5 + 2, h, sYT, sFI, Xw, yw, Em, IE, outC, lo);
            step_i<3>(t5 + 3, h, sYT, sFI, Xw, yw, Em, IE, outC, lo);
            step_i<4>(t5 + 4, h, sYT, sFI, Xw, yw, Em, IE, outC, lo);
        }
        step_i<0>(20, h, sYT, sFI, Xw, yw, Em, IE, outC, lo);
        step_i<1>(21, h, sYT, sFI, Xw, yw, Em, IE, outC, lo);
        step_i<2>(22, h, sYT, sFI, Xw, yw, Em, IE, outC, lo);
        step_i<3>(23, h, sYT, sFI, Xw, yw, Em, IE, outC, lo);
    }
}

extern "C" void kernel_launch(void* const* d_in, const int* in_sizes, int n_in,
                              void* d_out, int out_size, void* d_ws, size_t ws_size,
                              hipStream_t stream) {
    const float* X = (const float*)d_in[0];
    const float* Y = (const float*)d_in[1];
    float* out = (float*)d_out;
    ncc_kernel<<<dim3(16 * 32), dim3(NT), 0, stream>>>(X, Y, out);
}